// Round 13
// baseline (1013.902 us; speedup 1.0000x reference)
//
#include <hip/hip_runtime.h>
#include <hip/hip_bf16.h>

#define TT 512
#define DD 256
#define NH 4
#define NN 4096
#define VV 256
#define NLAYER 6
#define BB 2
#define BH (BB * NH)
#define NPAIR 2048

typedef __attribute__((ext_vector_type(8))) short bf16x8;
typedef __attribute__((ext_vector_type(4))) float f32x4;
typedef __attribute__((ext_vector_type(8))) unsigned short us8;

#define AS1 __attribute__((address_space(1)))
#define AS3 __attribute__((address_space(3)))

__device__ __forceinline__ void glds16(const unsigned short* g, unsigned short* l) {
  __builtin_amdgcn_global_load_lds((const AS1 void*)g, (AS3 void*)l, 16, 0, 0);
}

__device__ __forceinline__ unsigned short f2bf(float f) {
  unsigned int u = __float_as_uint(f);
  return (unsigned short)((u + 0x7FFFu + ((u >> 16) & 1u)) >> 16);
}
__device__ __forceinline__ float bf2f(unsigned short h) {
  return __uint_as_float((unsigned int)h << 16);
}

// ---------------- block-wide sum over 256 threads ----------------
__device__ __forceinline__ float block_sum_256(float v) {
  __shared__ float s[4];
  #pragma unroll
  for (int o = 32; o > 0; o >>= 1) v += __shfl_down(v, o);
  int lane = threadIdx.x & 63, wid = threadIdx.x >> 6;
  if (lane == 0) s[wid] = v;
  __syncthreads();
  float r = s[0] + s[1] + s[2] + s[3];
  __syncthreads();
  return r;
}

// ---- 128x128 MFMA tile, glds staging (m97 pattern): C = A(128xK)·B(128xK)^T ----
// As/Bs: [128][32] unpadded K-contig us tiles (8 KB each).
// wave w stages rows [w*32,w*32+32) of A and B via 4 glds/K-step.
__device__ __forceinline__ void mfma_tile128_glds(const unsigned short* __restrict__ A, int lda,
                                                  const unsigned short* __restrict__ B, int ldb,
                                                  int K, f32x4 acc[4][4],
                                                  unsigned short* As, unsigned short* Bs) {
  const int tid = threadIdx.x;
  const int lane = tid & 63, wave = tid >> 6;
  const int fm = lane & 15, fq = lane >> 4;
  const int rw = (wave >> 1) << 6, cw = (wave & 1) << 6;
  const int lrow = lane >> 2, lcol = (lane & 3) << 3;
  const unsigned short* gA = A + (size_t)(wave * 32 + lrow) * lda + lcol;
  const unsigned short* gB = B + (size_t)(wave * 32 + lrow) * ldb + lcol;
  unsigned short* lA = As + wave * 32 * 32;   // wave-uniform LDS base
  unsigned short* lB = Bs + wave * 32 * 32;
  for (int k0 = 0; k0 < K; k0 += 32) {
    __syncthreads();                          // prior ds_reads done before overwrite
    glds16(gA + k0,                    lA);
    glds16(gA + k0 + (size_t)16 * lda, lA + 16 * 32);
    glds16(gB + k0,                    lB);
    glds16(gB + k0 + (size_t)16 * ldb, lB + 16 * 32);
    __syncthreads();                          // drains vmcnt before barrier
    bf16x8 af[4], bfv[4];
    #pragma unroll
    for (int i = 0; i < 4; ++i) {
      af[i]  = *(const bf16x8*)(As + (rw + i * 16 + fm) * 32 + (fq << 3));
      bfv[i] = *(const bf16x8*)(Bs + (cw + i * 16 + fm) * 32 + (fq << 3));
    }
    #pragma unroll
    for (int mi = 0; mi < 4; ++mi)
      #pragma unroll
      for (int ni = 0; ni < 4; ++ni)
        acc[mi][ni] = __builtin_amdgcn_mfma_f32_16x16x32_bf16(af[mi], bfv[ni], acc[mi][ni], 0, 0, 0);
  }
}
// C/D: row = m0 + rw + mi*16 + (lane>>4)*4 + r ; col = n0 + cw + ni*16 + (lane&15)

// ---------------- small kernels ----------------

__global__ __launch_bounds__(256) void k_csinit(float2* __restrict__ cs) {
  int idx = blockIdx.x * 256 + threadIdx.x;
  int t = idx >> 11, p = idx & (NPAIR - 1);
  const float INV2PI = 0.15915494309189535f;
  const float TWOPI = 6.283185307179586f;
  float f = exp2f(-16.0f * (float)(2 * p) / (float)NN) * INV2PI;
  float ph = fmodf((float)t * f, 1.0f) * TWOPI;
  float s, c;
  sincosf(ph, &s, &c);
  cs[idx] = make_float2(c, s);
}

__global__ __launch_bounds__(256) void k_tcast(const float* __restrict__ in,
                                               unsigned short* __restrict__ out,
                                               int R, int C) {
  __shared__ float tile[64][65];
  const size_t zoff = (size_t)blockIdx.z * R * C;
  const int r0 = blockIdx.y * 64, c0 = blockIdx.x * 64;
  const int cl = threadIdx.x & 63, r4 = threadIdx.x >> 6;
  #pragma unroll 4
  for (int i = 0; i < 16; ++i) {
    int rl = r4 * 16 + i;
    tile[rl][cl] = in[zoff + (size_t)(r0 + rl) * C + c0 + cl];
  }
  __syncthreads();
  #pragma unroll 4
  for (int i = 0; i < 16; ++i) {
    int ccl = r4 * 16 + i;
    out[zoff + (size_t)(c0 + ccl) * R + r0 + cl] = f2bf(tile[cl][ccl]);
  }
}

// x[b,t,:] = LN(embed[ids]); emits f32 x, bf16 xbf, bf16 xT
__global__ __launch_bounds__(256) void k_embed_ln(const int* __restrict__ idw,
                                                  const float* __restrict__ tbl,
                                                  float* __restrict__ x,
                                                  unsigned short* __restrict__ xbf,
                                                  unsigned short* __restrict__ xTbf) {
  __shared__ int s_id;
  int row = blockIdx.x, tid = threadIdx.x;
  if (tid == 0) {
    bool is64 = true;
    for (int i = 1; i < 64; i += 2)
      if (idw[i] != 0) { is64 = false; break; }
    s_id = is64 ? idw[2 * row] : idw[row];
  }
  __syncthreads();
  int id = s_id;
  float v = tbl[(size_t)id * DD + tid];
  float mu = block_sum_256(v) * (1.0f / DD);
  float d = v - mu;
  float var = block_sum_256(d * d) * (1.0f / DD);
  float r = d * rsqrtf(var + 1e-5f);
  x[(size_t)row * DD + tid] = r;
  unsigned short rb = f2bf(r);
  xbf[(size_t)row * DD + tid] = rb;
  int b = row >> 9, t = row & 511;
  xTbf[((size_t)b * DD + tid) * TT + t] = rb;
}

// ---------------- GEMM kernels ----------------

// xsp = bf16(relu(x @ enc[h])); qr = bf16(rope(relu)) — glds main loop + LDS-transposed epilogue
__global__ __launch_bounds__(256) void k_enc(const unsigned short* __restrict__ xbf,
                                             const unsigned short* __restrict__ encT,
                                             const float2* __restrict__ cs,
                                             unsigned short* __restrict__ xsp,
                                             unsigned short* __restrict__ qr) {
  __shared__ float smemf[4224];  // 16896 B: As(8K)+Bs(8K) in loop; Sc 32x132 f32 in epilogue
  unsigned short* As = (unsigned short*)smemf;
  unsigned short* Bs = As + 4096;
  float (*Sc)[132] = (float(*)[132])smemf;
  const int tid = threadIdx.x;
  const int bh = blockIdx.z, b = bh >> 2, h = bh & 3;
  const int m0 = blockIdx.y * 128, n0 = blockIdx.x * 128;
  f32x4 acc[4][4] = {};
  mfma_tile128_glds(xbf + (size_t)b * TT * DD + (size_t)m0 * DD, DD,
                    encT + (size_t)h * NN * DD + (size_t)n0 * DD, DD, DD, acc, As, Bs);
  const int lane = tid & 63, wave = tid >> 6;
  const int fm = lane & 15, fq = lane >> 4;
  const int cw = (wave & 1) << 6;
  const int rbase = ((wave >> 1) << 4) + (fq << 2);
  const size_t base = (size_t)bh * TT * NN;
  const int rr = tid >> 3, cc = (tid & 7) << 4;
  #pragma unroll
  for (int mi = 0; mi < 4; ++mi) {
    __syncthreads();
    #pragma unroll
    for (int ni = 0; ni < 4; ++ni)
      #pragma unroll
      for (int r = 0; r < 4; ++r)
        Sc[rbase + r][cw + ni * 16 + fm] = acc[mi][ni][r];
    __syncthreads();
    float v[16];
    *(float4*)&v[0]  = *(const float4*)&Sc[rr][cc];
    *(float4*)&v[4]  = *(const float4*)&Sc[rr][cc + 4];
    *(float4*)&v[8]  = *(const float4*)&Sc[rr][cc + 8];
    *(float4*)&v[12] = *(const float4*)&Sc[rr][cc + 12];
    const int t = m0 + ((rr >> 4) << 6) + mi * 16 + (rr & 15);
    const int n = n0 + cc;
    #pragma unroll
    for (int j = 0; j < 16; ++j) v[j] = fmaxf(v[j], 0.0f);
    us8 o0, o1;
    #pragma unroll
    for (int j = 0; j < 8; ++j) { o0[j] = f2bf(v[j]); o1[j] = f2bf(v[8 + j]); }
    size_t off = base + (size_t)t * NN + n;
    *(us8*)(xsp + off) = o0;
    *(us8*)(xsp + off + 8) = o1;
    float cv[16];
    const float* cp = (const float*)(cs + (size_t)t * NPAIR + (n >> 1));
    *(float4*)&cv[0]  = *(const float4*)(cp);
    *(float4*)&cv[4]  = *(const float4*)(cp + 4);
    *(float4*)&cv[8]  = *(const float4*)(cp + 8);
    *(float4*)&cv[12] = *(const float4*)(cp + 12);
    us8 q0, q1;
    #pragma unroll
    for (int j = 0; j < 8; ++j) {
      float c = cv[2 * j], s = cv[2 * j + 1];
      float ve = v[2 * j], vo = v[2 * j + 1];
      float qe = ve * c - vo * s;
      float qo = vo * c + ve * s;
      if (j < 4) { q0[2 * j] = f2bf(qe); q0[2 * j + 1] = f2bf(qo); }
      else       { q1[2 * (j - 4)] = f2bf(qe); q1[2 * (j - 4) + 1] = f2bf(qo); }
    }
    *(us8*)(qr + off) = q0;
    *(us8*)(qr + off + 8) = q1;
  }
}

// scores partials: scp[bh*4+kc] = qr[:,kc*1024:+1024] · qr^T chunk (f32)
__global__ __launch_bounds__(256) void k_scores_part(const unsigned short* __restrict__ qr,
                                                     float* __restrict__ scp) {
  __shared__ float smemf[4096];  // 16 KB: As+Bs
  unsigned short* As = (unsigned short*)smemf;
  unsigned short* Bs = As + 4096;
  const int z = blockIdx.z, bh = z >> 2, kc = z & 3;
  const int m0 = blockIdx.y * 128, n0 = blockIdx.x * 128;
  if (n0 > m0) return;  // masked region handled in k_ykv_ln staging
  const unsigned short* Q = qr + (size_t)bh * TT * NN + kc * 1024;
  f32x4 acc[4][4] = {};
  mfma_tile128_glds(Q + (size_t)m0 * NN, NN, Q + (size_t)n0 * NN, NN, 1024, acc, As, Bs);
  const int lane = threadIdx.x & 63, wave = threadIdx.x >> 6;
  const int fm = lane & 15, fq = lane >> 4;
  const int rw = (wave >> 1) << 6, cw = (wave & 1) << 6;
  float* C = scp + (size_t)z * TT * TT;
  #pragma unroll
  for (int ni = 0; ni < 4; ++ni) {
    int s = n0 + cw + ni * 16 + fm;
    #pragma unroll
    for (int mi = 0; mi < 4; ++mi) {
      int trow = m0 + rw + mi * 16 + (fq << 2);
      #pragma unroll
      for (int r = 0; r < 4; ++r)
        C[(size_t)(trow + r) * TT + s] = acc[mi][ni][r];
    }
  }
}

// ykvbf = bf16(LN((masked sum of scp) @ x)) — 64x256 wide tile, LN fused
__global__ __launch_bounds__(256) void k_ykv_ln(const float* __restrict__ scp,
                                                const unsigned short* __restrict__ xTbf,
                                                unsigned short* __restrict__ ykvbf) {
  __shared__ unsigned short As[64][40];
  __shared__ unsigned short Bs[256][40];
  const int tid = threadIdx.x;
  const int m0 = blockIdx.x * 64, bh = blockIdx.y, b = bh >> 2;
  const int lane = tid & 63, wave = tid >> 6;
  const int srow = tid >> 2, sk = (tid & 3) << 3;
  const int fm = lane & 15, fq = lane >> 4;
  const int t = m0 + srow;
  const size_t abase0 = (size_t)(bh * 4) * TT * TT + (size_t)t * TT;
  const unsigned short* Brow = xTbf + ((size_t)b * DD + tid) * TT;
  f32x4 acc[16] = {};
  for (int k0 = 0; k0 < TT; k0 += 32) {
    us8 av;
    const int s0 = k0 + sk;
    if (s0 >= t) {
      #pragma unroll
      for (int j = 0; j < 8; ++j) av[j] = 0;
    } else {
      const float* p = scp + abase0 + s0;
      float sum[8];
      #pragma unroll
      for (int j = 0; j < 8; ++j) sum[j] = 0.0f;
      #pragma unroll
      for (int kc = 0; kc < 4; ++kc) {
        float4 u0 = *(const float4*)(p + (size_t)kc * TT * TT);
        float4 u1 = *(const float4*)(p + (size_t)kc * TT * TT + 4);
        sum[0] += u0.x; sum[1] += u0.y; sum[2] += u0.z; sum[3] += u0.w;
        sum[4] += u1.x; sum[5] += u1.y; sum[6] += u1.z; sum[7] += u1.w;
      }
      #pragma unroll
      for (int j = 0; j < 8; ++j)
        av[j] = f2bf((s0 + j < t) ? sum[j] : 0.0f);
    }
    us8 bv0 = *(const us8*)(Brow + k0);
    us8 bv1 = *(const us8*)(Brow + k0 + 8);
    us8 bv2 = *(const us8*)(Brow + k0 + 16);
    us8 bv3 = *(const us8*)(Brow + k0 + 24);
    __syncthreads();
    *(us8*)(&As[srow][sk]) = av;
    *(us8*)(&Bs[tid][0]) = bv0;
    *(us8*)(&Bs[tid][8]) = bv1;
    *(us8*)(&Bs[tid][16]) = bv2;
    *(us8*)(&Bs[tid][24]) = bv3;
    __syncthreads();
    bf16x8 a = *(const bf16x8*)(&As[wave * 16 + fm][fq << 3]);
    #pragma unroll
    for (int ni = 0; ni < 16; ++ni) {
      bf16x8 bfr = *(const bf16x8*)(&Bs[ni * 16 + fm][fq << 3]);
      acc[ni] = __builtin_amdgcn_mfma_f32_16x16x32_bf16(a, bfr, acc[ni], 0, 0, 0);
    }
  }
  float p1[4], p2[4];
  #pragma unroll
  for (int r = 0; r < 4; ++r) { p1[r] = 0.0f; p2[r] = 0.0f; }
  #pragma unroll
  for (int ni = 0; ni < 16; ++ni)
    #pragma unroll
    for (int r = 0; r < 4; ++r) {
      float v = acc[ni][r];
      p1[r] += v; p2[r] += v * v;
    }
  #pragma unroll
  for (int off = 1; off < 16; off <<= 1)
    #pragma unroll
    for (int r = 0; r < 4; ++r) {
      p1[r] += __shfl_xor(p1[r], off);
      p2[r] += __shfl_xor(p2[r], off);
    }
  const int trow = m0 + wave * 16 + (fq << 2);
  #pragma unroll
  for (int r = 0; r < 4; ++r) {
    float mu = p1[r] * (1.0f / DD);
    float var = p2[r] * (1.0f / DD) - mu * mu;
    float sc = rsqrtf(var + 1e-5f);
    unsigned short* C = ykvbf + ((size_t)bh * TT + trow + r) * DD;
    #pragma unroll
    for (int ni = 0; ni < 16; ++ni)
      C[ni * 16 + fm] = f2bf((acc[ni][r] - mu) * sc);
  }
}

// xy_bf = xsp_bf * relu(ykv_bf @ encv[h]) — glds main loop + LDS-transposed epilogue
__global__ __launch_bounds__(256) void k_ysp_xy(const unsigned short* __restrict__ ykvbf,
                                                const unsigned short* __restrict__ encvT,
                                                const unsigned short* __restrict__ xsp,
                                                unsigned short* __restrict__ xy) {
  __shared__ float smemf[4224];
  unsigned short* As = (unsigned short*)smemf;
  unsigned short* Bs = As + 4096;
  float (*Sc)[132] = (float(*)[132])smemf;
  const int tid = threadIdx.x;
  const int bh = blockIdx.z, h = bh & 3;
  const int m0 = blockIdx.y * 128, n0 = blockIdx.x * 128;
  f32x4 acc[4][4] = {};
  mfma_tile128_glds(ykvbf + (size_t)bh * TT * DD + (size_t)m0 * DD, DD,
                    encvT + (size_t)h * NN * DD + (size_t)n0 * DD, DD, DD, acc, As, Bs);
  const int lane = tid & 63, wave = tid >> 6;
  const int fm = lane & 15, fq = lane >> 4;
  const int cw = (wave & 1) << 6;
  const int rbase = ((wave >> 1) << 4) + (fq << 2);
  const size_t base = (size_t)bh * TT * NN;
  const int rr = tid >> 3, cc = (tid & 7) << 4;
  #pragma unroll
  for (int mi = 0; mi < 4; ++mi) {
    __syncthreads();
    #pragma unroll
    for (int ni = 0; ni < 4; ++ni)
      #pragma unroll
      for (int r = 0; r < 4; ++r)
        Sc[rbase + r][cw + ni * 16 + fm] = acc[mi][ni][r];
    __syncthreads();
    float v[16];
    *(float4*)&v[0]  = *(const float4*)&Sc[rr][cc];
    *(float4*)&v[4]  = *(const float4*)&Sc[rr][cc + 4];
    *(float4*)&v[8]  = *(const float4*)&Sc[rr][cc + 8];
    *(float4*)&v[12] = *(const float4*)&Sc[rr][cc + 12];
    const int t = m0 + ((rr >> 4) << 6) + mi * 16 + (rr & 15);
    const int n = n0 + cc;
    size_t off = base + (size_t)t * NN + n;
    us8 x0 = *(const us8*)(xsp + off);
    us8 x1 = *(const us8*)(xsp + off + 8);
    us8 o0, o1;
    #pragma unroll
    for (int j = 0; j < 8; ++j) {
      o0[j] = f2bf(bf2f(x0[j]) * fmaxf(v[j], 0.0f));
      o1[j] = f2bf(bf2f(x1[j]) * fmaxf(v[8 + j], 0.0f));
    }
    *(us8*)(xy + off) = o0;
    *(us8*)(xy + off + 8) = o1;
  }
}

// ym32[bh*8+ks] = xy_bf chunk @ dec[h] chunk  (K-split 8)
__global__ __launch_bounds__(256) void k_ymlp(const unsigned short* __restrict__ xy,
                                              const unsigned short* __restrict__ decT,
                                              float* __restrict__ ym32) {
  __shared__ float smemf[4096];
  unsigned short* As = (unsigned short*)smemf;
  unsigned short* Bs = As + 4096;
  const int z = blockIdx.z, bh = z >> 3, ks = z & 7, h = bh & 3;
  const int m0 = blockIdx.y * 128, n0 = blockIdx.x * 128;
  f32x4 acc[4][4] = {};
  mfma_tile128_glds(xy + (size_t)bh * TT * NN + (size_t)m0 * NN + ks * 512, NN,
                    decT + (size_t)h * DD * NN + (size_t)n0 * NN + ks * 512, NN,
                    512, acc, As, Bs);
  const int lane = threadIdx.x & 63, wave = threadIdx.x >> 6;
  const int fm = lane & 15, fq = lane >> 4;
  const int rw = (wave >> 1) << 6, cw = (wave & 1) << 6;
  float* C = ym32 + (size_t)z * TT * DD;
  #pragma unroll
  for (int ni = 0; ni < 4; ++ni) {
    int d = n0 + cw + ni * 16 + fm;
    #pragma unroll
    for (int mi = 0; mi < 4; ++mi) {
      int trow = m0 + rw + mi * 16 + (fq << 2);
      #pragma unroll
      for (int r = 0; r < 4; ++r)
        C[(size_t)(trow + r) * DD + d] = acc[mi][ni][r];
    }
  }
}

// x = LN(x + LN(sum of 32 partials)); emits f32 x, bf16 xbf, bf16 xT
__global__ __launch_bounds__(256) void k_ln2(float* __restrict__ x,
                                             const float* __restrict__ ym32,
                                             unsigned short* __restrict__ xbf,
                                             unsigned short* __restrict__ xTbf) {
  int row = blockIdx.x, tid = threadIdx.x;
  int b = row >> 9, t = row & 511;
  float y = 0.0f;
  for (int p = 0; p < 32; ++p)
    y += ym32[(size_t)(b * 32 + p) * TT * DD + (size_t)t * DD + tid];
  float mu = block_sum_256(y) * (1.0f / DD);
  float d = y - mu;
  float var = block_sum_256(d * d) * (1.0f / DD);
  float ly = d * rsqrtf(var + 1e-5f);
  float xv = x[(size_t)row * DD + tid] + ly;
  float mu2 = block_sum_256(xv) * (1.0f / DD);
  float d2 = xv - mu2;
  float var2 = block_sum_256(d2 * d2) * (1.0f / DD);
  float r = d2 * rsqrtf(var2 + 1e-5f);
  x[(size_t)row * DD + tid] = r;
  unsigned short rb = f2bf(r);
  xbf[(size_t)row * DD + tid] = rb;
  xTbf[((size_t)b * DD + tid) * TT + t] = rb;
}

__global__ __launch_bounds__(256) void k_trace(const unsigned short* __restrict__ xy,
                                               float* __restrict__ out) {
  int idx = blockIdx.x * 256 + threadIdx.x;
  int b = idx >> 14, c = idx & 16383;
  int h = c >> 12, n = c & 4095;
  size_t base = (size_t)(b * 4 + h) * TT * NN + n;
  float s = 0.0f;
  for (int t = 0; t < TT; ++t) s += bf2f(xy[base + (size_t)t * NN]);
  out[idx] = s * (1.0f / TT);
}

__global__ __launch_bounds__(256) void k_logits(const float* __restrict__ x,
                                                const float* __restrict__ W,
                                                float* __restrict__ out) {
  __shared__ float xs[DD];
  int row = blockIdx.x, tid = threadIdx.x;
  xs[tid] = x[(size_t)row * DD + tid];
  __syncthreads();
  float s = 0.0f;
  #pragma unroll 8
  for (int d = 0; d < DD; ++d) s = fmaf(xs[d], W[(size_t)d * VV + tid], s);
  out[(size_t)row * VV + tid] = s;
}

__global__ __launch_bounds__(256) void k_embedding(const float* __restrict__ x,
                                                   float* __restrict__ out) {
  int idx = blockIdx.x * 256 + threadIdx.x;
  int b = idx >> 8, d = idx & 255;
  float s = 0.0f;
  for (int t = 0; t < TT; ++t) s += x[(size_t)(b * TT + t) * DD + d];
  out[idx] = s * (1.0f / TT);
}

extern "C" void kernel_launch(void* const* d_in, const int* in_sizes, int n_in,
                              void* d_out, int out_size, void* d_ws, size_t ws_size,
                              hipStream_t stream) {
  const int*   ids  = (const int*)d_in[0];
  const float* tbl  = (const float*)d_in[1];
  const float* enc  = (const float*)d_in[2];
  const float* encv = (const float*)d_in[3];
  const float* dec  = (const float*)d_in[4];
  const float* lmh  = (const float*)d_in[5];

  // workspace layout (float units), ~164 MiB total
  float* ws   = (float*)d_ws;
  float* x    = ws;                                              //   262,144 f
  unsigned short* ykvbf = (unsigned short*)(x + 262144);         // 1,048,576 us
  float* ym32 = (float*)(ykvbf + 1048576);                       // 8,388,608 f
  unsigned short* xbf   = (unsigned short*)(ym32 + 8388608);     //   262,144 us
  unsigned short* xTbf  = xbf + 262144;                          //   262,144 us
  unsigned short* encT  = xTbf + 262144;                         // 4,194,304 us
  unsigned short* encvT = encT + 4194304;                        // 4,194,304 us
  unsigned short* decT  = encvT + 4194304;                       // 4,194,304 us
  unsigned short* xspbf = decT + 4194304;                        // 16,777,216 us
  unsigned short* qxybf = xspbf + 16777216;                      // 16,777,216 us
  float2* cs  = (float2*)(qxybf + 16777216);                     // 1,048,576 float2
  float* scp  = (float*)(cs + 1048576);                          // 8,388,608 f (32 MiB)

  float* out_logits = (float*)d_out;
  float* out_embed  = out_logits + (size_t)BB * TT * VV;
  float* out_trace  = out_embed + (size_t)BB * DD;

  k_csinit<<<(TT * NPAIR) / 256, 256, 0, stream>>>(cs);
  k_tcast<<<dim3(NN / 64, DD / 64, NH), 256, 0, stream>>>(enc,  encT,  DD, NN);
  k_tcast<<<dim3(NN / 64, DD / 64, NH), 256, 0, stream>>>(encv, encvT, DD, NN);
  k_tcast<<<dim3(DD / 64, NN / 64, NH), 256, 0, stream>>>(dec,  decT,  NN, DD);

  k_embed_ln<<<BB * TT, 256, 0, stream>>>(ids, tbl, x, xbf, xTbf);
  for (int l = 0; l < NLAYER; ++l) {
    k_enc        <<<dim3(NN / 128, TT / 128, BH), 256, 0, stream>>>(xbf, encT, cs, xspbf, qxybf);
    k_scores_part<<<dim3(TT / 128, TT / 128, BH * 4), 256, 0, stream>>>(qxybf, scp);
    k_ykv_ln     <<<dim3(TT / 64, BH), 256, 0, stream>>>(scp, xTbf, ykvbf);
    k_ysp_xy     <<<dim3(NN / 128, TT / 128, BH), 256, 0, stream>>>(ykvbf, encvT, xspbf, qxybf);
    k_ymlp       <<<dim3(DD / 128, TT / 128, BH * 8), 256, 0, stream>>>(qxybf, decT, ym32);
    k_ln2        <<<BB * TT, 256, 0, stream>>>(x, ym32, xbf, xTbf);
  }
  k_trace    <<<(BB * NH * NN) / 256, 256, 0, stream>>>(qxybf, out_trace);
  k_logits   <<<BB * TT, 256, 0, stream>>>(x, lmh, out_logits);
  k_embedding<<<(BB * DD) / 256, 256, 0, stream>>>(x, out_embed);
}

// Round 14
// 952.065 us; speedup vs baseline: 1.0650x; 1.0650x over previous
//
#include <hip/hip_runtime.h>
#include <hip/hip_bf16.h>

#define TT 512
#define DD 256
#define NH 4
#define NN 4096
#define VV 256
#define NLAYER 6
#define BB 2
#define BH (BB * NH)
#define NPAIR 2048

typedef __attribute__((ext_vector_type(8))) short bf16x8;
typedef __attribute__((ext_vector_type(4))) float f32x4;
typedef __attribute__((ext_vector_type(8))) unsigned short us8;

#define AS1 __attribute__((address_space(1)))
#define AS3 __attribute__((address_space(3)))

__device__ __forceinline__ void glds16(const unsigned short* g, unsigned short* l) {
  __builtin_amdgcn_global_load_lds((const AS1 void*)g, (AS3 void*)l, 16, 0, 0);
}

__device__ __forceinline__ unsigned short f2bf(float f) {
  unsigned int u = __float_as_uint(f);
  return (unsigned short)((u + 0x7FFFu + ((u >> 16) & 1u)) >> 16);
}
__device__ __forceinline__ float bf2f(unsigned short h) {
  return __uint_as_float((unsigned int)h << 16);
}

// ---------------- block-wide sum over 256 threads ----------------
__device__ __forceinline__ float block_sum_256(float v) {
  __shared__ float s[4];
  #pragma unroll
  for (int o = 32; o > 0; o >>= 1) v += __shfl_down(v, o);
  int lane = threadIdx.x & 63, wid = threadIdx.x >> 6;
  if (lane == 0) s[wid] = v;
  __syncthreads();
  float r = s[0] + s[1] + s[2] + s[3];
  __syncthreads();
  return r;
}

// ---- 128x128 MFMA tile, glds staging (m97 pattern): C = A(128xK)·B(128xK)^T ----
__device__ __forceinline__ void mfma_tile128_glds(const unsigned short* __restrict__ A, int lda,
                                                  const unsigned short* __restrict__ B, int ldb,
                                                  int K, f32x4 acc[4][4],
                                                  unsigned short* As, unsigned short* Bs) {
  const int tid = threadIdx.x;
  const int lane = tid & 63, wave = tid >> 6;
  const int fm = lane & 15, fq = lane >> 4;
  const int rw = (wave >> 1) << 6, cw = (wave & 1) << 6;
  const int lrow = lane >> 2, lcol = (lane & 3) << 3;
  const unsigned short* gA = A + (size_t)(wave * 32 + lrow) * lda + lcol;
  const unsigned short* gB = B + (size_t)(wave * 32 + lrow) * ldb + lcol;
  unsigned short* lA = As + wave * 32 * 32;
  unsigned short* lB = Bs + wave * 32 * 32;
  for (int k0 = 0; k0 < K; k0 += 32) {
    __syncthreads();
    glds16(gA + k0,                    lA);
    glds16(gA + k0 + (size_t)16 * lda, lA + 16 * 32);
    glds16(gB + k0,                    lB);
    glds16(gB + k0 + (size_t)16 * ldb, lB + 16 * 32);
    __syncthreads();
    bf16x8 af[4], bfv[4];
    #pragma unroll
    for (int i = 0; i < 4; ++i) {
      af[i]  = *(const bf16x8*)(As + (rw + i * 16 + fm) * 32 + (fq << 3));
      bfv[i] = *(const bf16x8*)(Bs + (cw + i * 16 + fm) * 32 + (fq << 3));
    }
    #pragma unroll
    for (int mi = 0; mi < 4; ++mi)
      #pragma unroll
      for (int ni = 0; ni < 4; ++ni)
        acc[mi][ni] = __builtin_amdgcn_mfma_f32_16x16x32_bf16(af[mi], bfv[ni], acc[mi][ni], 0, 0, 0);
  }
}
// C/D: row = m0 + rw + mi*16 + (lane>>4)*4 + r ; col = n0 + cw + ni*16 + (lane&15)

// ---------------- small kernels ----------------

__global__ __launch_bounds__(256) void k_csinit(float2* __restrict__ cs) {
  int idx = blockIdx.x * 256 + threadIdx.x;
  int t = idx >> 11, p = idx & (NPAIR - 1);
  const float INV2PI = 0.15915494309189535f;
  const float TWOPI = 6.283185307179586f;
  float f = exp2f(-16.0f * (float)(2 * p) / (float)NN) * INV2PI;
  float ph = fmodf((float)t * f, 1.0f) * TWOPI;
  float s, c;
  sincosf(ph, &s, &c);
  cs[idx] = make_float2(c, s);
}

__global__ __launch_bounds__(256) void k_tcast(const float* __restrict__ in,
                                               unsigned short* __restrict__ out,
                                               int R, int C) {
  __shared__ float tile[64][65];
  const size_t zoff = (size_t)blockIdx.z * R * C;
  const int r0 = blockIdx.y * 64, c0 = blockIdx.x * 64;
  const int cl = threadIdx.x & 63, r4 = threadIdx.x >> 6;
  #pragma unroll 4
  for (int i = 0; i < 16; ++i) {
    int rl = r4 * 16 + i;
    tile[rl][cl] = in[zoff + (size_t)(r0 + rl) * C + c0 + cl];
  }
  __syncthreads();
  #pragma unroll 4
  for (int i = 0; i < 16; ++i) {
    int ccl = r4 * 16 + i;
    out[zoff + (size_t)(c0 + ccl) * R + r0 + cl] = f2bf(tile[cl][ccl]);
  }
}

// x[b,t,:] = LN(embed[ids]); emits f32 x, bf16 xbf, bf16 xT
__global__ __launch_bounds__(256) void k_embed_ln(const int* __restrict__ idw,
                                                  const float* __restrict__ tbl,
                                                  float* __restrict__ x,
                                                  unsigned short* __restrict__ xbf,
                                                  unsigned short* __restrict__ xTbf) {
  __shared__ int s_id;
  int row = blockIdx.x, tid = threadIdx.x;
  if (tid == 0) {
    bool is64 = true;
    for (int i = 1; i < 64; i += 2)
      if (idw[i] != 0) { is64 = false; break; }
    s_id = is64 ? idw[2 * row] : idw[row];
  }
  __syncthreads();
  int id = s_id;
  float v = tbl[(size_t)id * DD + tid];
  float mu = block_sum_256(v) * (1.0f / DD);
  float d = v - mu;
  float var = block_sum_256(d * d) * (1.0f / DD);
  float r = d * rsqrtf(var + 1e-5f);
  x[(size_t)row * DD + tid] = r;
  unsigned short rb = f2bf(r);
  xbf[(size_t)row * DD + tid] = rb;
  int b = row >> 9, t = row & 511;
  xTbf[((size_t)b * DD + tid) * TT + t] = rb;
}

// ---------------- GEMM kernels ----------------

// xsp = bf16(relu(x @ enc[h])); qr = bf16(rope(relu)) — glds + LDS-transposed epilogue
__global__ __launch_bounds__(256) void k_enc(const unsigned short* __restrict__ xbf,
                                             const unsigned short* __restrict__ encT,
                                             const float2* __restrict__ cs,
                                             unsigned short* __restrict__ xsp,
                                             unsigned short* __restrict__ qr) {
  __shared__ float smemf[4224];
  unsigned short* As = (unsigned short*)smemf;
  unsigned short* Bs = As + 4096;
  float (*Sc)[132] = (float(*)[132])smemf;
  const int tid = threadIdx.x;
  const int bh = blockIdx.z, b = bh >> 2, h = bh & 3;
  const int m0 = blockIdx.y * 128, n0 = blockIdx.x * 128;
  f32x4 acc[4][4] = {};
  mfma_tile128_glds(xbf + (size_t)b * TT * DD + (size_t)m0 * DD, DD,
                    encT + (size_t)h * NN * DD + (size_t)n0 * DD, DD, DD, acc, As, Bs);
  const int lane = tid & 63, wave = tid >> 6;
  const int fm = lane & 15, fq = lane >> 4;
  const int cw = (wave & 1) << 6;
  const int rbase = ((wave >> 1) << 4) + (fq << 2);
  const size_t base = (size_t)bh * TT * NN;
  const int rr = tid >> 3, cc = (tid & 7) << 4;
  #pragma unroll
  for (int mi = 0; mi < 4; ++mi) {
    __syncthreads();
    #pragma unroll
    for (int ni = 0; ni < 4; ++ni)
      #pragma unroll
      for (int r = 0; r < 4; ++r)
        Sc[rbase + r][cw + ni * 16 + fm] = acc[mi][ni][r];
    __syncthreads();
    float v[16];
    *(float4*)&v[0]  = *(const float4*)&Sc[rr][cc];
    *(float4*)&v[4]  = *(const float4*)&Sc[rr][cc + 4];
    *(float4*)&v[8]  = *(const float4*)&Sc[rr][cc + 8];
    *(float4*)&v[12] = *(const float4*)&Sc[rr][cc + 12];
    const int t = m0 + ((rr >> 4) << 6) + mi * 16 + (rr & 15);
    const int n = n0 + cc;
    #pragma unroll
    for (int j = 0; j < 16; ++j) v[j] = fmaxf(v[j], 0.0f);
    us8 o0, o1;
    #pragma unroll
    for (int j = 0; j < 8; ++j) { o0[j] = f2bf(v[j]); o1[j] = f2bf(v[8 + j]); }
    size_t off = base + (size_t)t * NN + n;
    *(us8*)(xsp + off) = o0;
    *(us8*)(xsp + off + 8) = o1;
    float cv[16];
    const float* cp = (const float*)(cs + (size_t)t * NPAIR + (n >> 1));
    *(float4*)&cv[0]  = *(const float4*)(cp);
    *(float4*)&cv[4]  = *(const float4*)(cp + 4);
    *(float4*)&cv[8]  = *(const float4*)(cp + 8);
    *(float4*)&cv[12] = *(const float4*)(cp + 12);
    us8 q0, q1;
    #pragma unroll
    for (int j = 0; j < 8; ++j) {
      float c = cv[2 * j], s = cv[2 * j + 1];
      float ve = v[2 * j], vo = v[2 * j + 1];
      float qe = ve * c - vo * s;
      float qo = vo * c + ve * s;
      if (j < 4) { q0[2 * j] = f2bf(qe); q0[2 * j + 1] = f2bf(qo); }
      else       { q1[2 * (j - 4)] = f2bf(qe); q1[2 * (j - 4) + 1] = f2bf(qo); }
    }
    *(us8*)(qr + off) = q0;
    *(us8*)(qr + off + 8) = q1;
  }
}

// scores partials: scp[bh*4+kc] = qr[:,kc*1024:+1024] · qr^T chunk (f32)
__global__ __launch_bounds__(256) void k_scores_part(const unsigned short* __restrict__ qr,
                                                     float* __restrict__ scp) {
  __shared__ float smemf[4096];
  unsigned short* As = (unsigned short*)smemf;
  unsigned short* Bs = As + 4096;
  const int z = blockIdx.z, bh = z >> 2, kc = z & 3;
  const int m0 = blockIdx.y * 128, n0 = blockIdx.x * 128;
  if (n0 > m0) return;  // masked region handled in k_ykv_part staging
  const unsigned short* Q = qr + (size_t)bh * TT * NN + kc * 1024;
  f32x4 acc[4][4] = {};
  mfma_tile128_glds(Q + (size_t)m0 * NN, NN, Q + (size_t)n0 * NN, NN, 1024, acc, As, Bs);
  const int lane = threadIdx.x & 63, wave = threadIdx.x >> 6;
  const int fm = lane & 15, fq = lane >> 4;
  const int rw = (wave >> 1) << 6, cw = (wave & 1) << 6;
  float* C = scp + (size_t)z * TT * TT;
  #pragma unroll
  for (int ni = 0; ni < 4; ++ni) {
    int s = n0 + cw + ni * 16 + fm;
    #pragma unroll
    for (int mi = 0; mi < 4; ++mi) {
      int trow = m0 + rw + mi * 16 + (fq << 2);
      #pragma unroll
      for (int r = 0; r < 4; ++r)
        C[(size_t)(trow + r) * TT + s] = acc[mi][ni][r];
    }
  }
}

// ykv partials over s-chunks: ykvp[bh*4+ks] = (masked sum of scp)[:, ks*128:+128] @ x
// 64x256 wide tile per block; KS=4 restores grid width (256 blocks).
__global__ __launch_bounds__(256) void k_ykv_part(const float* __restrict__ scp,
                                                  const unsigned short* __restrict__ xTbf,
                                                  float* __restrict__ ykvp) {
  __shared__ unsigned short As[64][40];
  __shared__ unsigned short Bs[256][40];
  const int tid = threadIdx.x;
  const int m0 = blockIdx.x * 64, bh = blockIdx.y, ks = blockIdx.z, b = bh >> 2;
  float* C = ykvp + ((size_t)(bh * 4 + ks) * TT + m0) * DD;
  if (ks * 128 >= m0 + 64) {  // whole s-chunk masked: write zero partial
    float4 z = {0.0f, 0.0f, 0.0f, 0.0f};
    #pragma unroll
    for (int j = 0; j < 16; ++j)
      *(float4*)(C + (size_t)j * 1024 + tid * 4) = z;
    return;
  }
  const int lane = tid & 63, wave = tid >> 6;
  const int srow = tid >> 2, sk = (tid & 3) << 3;
  const int fm = lane & 15, fq = lane >> 4;
  const int t = m0 + srow;
  const size_t abase0 = (size_t)(bh * 4) * TT * TT + (size_t)t * TT;
  const unsigned short* Brow = xTbf + ((size_t)b * DD + tid) * TT + ks * 128;
  f32x4 acc[16] = {};
  for (int k0 = 0; k0 < 128; k0 += 32) {
    us8 av;
    const int s0 = ks * 128 + k0 + sk;
    if (s0 >= t) {
      #pragma unroll
      for (int j = 0; j < 8; ++j) av[j] = 0;
    } else {
      const float* p = scp + abase0 + s0;
      float sum[8];
      #pragma unroll
      for (int j = 0; j < 8; ++j) sum[j] = 0.0f;
      #pragma unroll
      for (int kc = 0; kc < 4; ++kc) {
        float4 u0 = *(const float4*)(p + (size_t)kc * TT * TT);
        float4 u1 = *(const float4*)(p + (size_t)kc * TT * TT + 4);
        sum[0] += u0.x; sum[1] += u0.y; sum[2] += u0.z; sum[3] += u0.w;
        sum[4] += u1.x; sum[5] += u1.y; sum[6] += u1.z; sum[7] += u1.w;
      }
      #pragma unroll
      for (int j = 0; j < 8; ++j)
        av[j] = f2bf((s0 + j < t) ? sum[j] : 0.0f);
    }
    us8 bv0 = *(const us8*)(Brow + k0);
    us8 bv1 = *(const us8*)(Brow + k0 + 8);
    us8 bv2 = *(const us8*)(Brow + k0 + 16);
    us8 bv3 = *(const us8*)(Brow + k0 + 24);
    __syncthreads();
    *(us8*)(&As[srow][sk]) = av;
    *(us8*)(&Bs[tid][0]) = bv0;
    *(us8*)(&Bs[tid][8]) = bv1;
    *(us8*)(&Bs[tid][16]) = bv2;
    *(us8*)(&Bs[tid][24]) = bv3;
    __syncthreads();
    bf16x8 a = *(const bf16x8*)(&As[wave * 16 + fm][fq << 3]);
    #pragma unroll
    for (int ni = 0; ni < 16; ++ni) {
      bf16x8 bfr = *(const bf16x8*)(&Bs[ni * 16 + fm][fq << 3]);
      acc[ni] = __builtin_amdgcn_mfma_f32_16x16x32_bf16(a, bfr, acc[ni], 0, 0, 0);
    }
  }
  const int trow = wave * 16 + (fq << 2);
  #pragma unroll
  for (int ni = 0; ni < 16; ++ni)
    #pragma unroll
    for (int r = 0; r < 4; ++r)
      C[(size_t)(trow + r) * DD + ni * 16 + fm] = acc[ni][r];
}

// ykvbf = bf16(LN(sum of 4 ykv partials))
__global__ __launch_bounds__(256) void k_ykv_red(const float* __restrict__ ykvp,
                                                 unsigned short* __restrict__ ykvbf) {
  int row = blockIdx.x, tid = threadIdx.x;  // row = bh*TT + t
  int bh = row >> 9, t = row & 511;
  size_t base = ((size_t)(bh * 4) * TT + t) * DD + tid;
  float v = ykvp[base] + ykvp[base + (size_t)TT * DD] +
            ykvp[base + (size_t)2 * TT * DD] + ykvp[base + (size_t)3 * TT * DD];
  float mu = block_sum_256(v) * (1.0f / DD);
  float d = v - mu;
  float var = block_sum_256(d * d) * (1.0f / DD);
  ykvbf[(size_t)row * DD + tid] = f2bf(d * rsqrtf(var + 1e-5f));
}

// xy_bf = xsp_bf * relu(ykv_bf @ encv[h]) — glds + LDS-transposed epilogue
__global__ __launch_bounds__(256) void k_ysp_xy(const unsigned short* __restrict__ ykvbf,
                                                const unsigned short* __restrict__ encvT,
                                                const unsigned short* __restrict__ xsp,
                                                unsigned short* __restrict__ xy) {
  __shared__ float smemf[4224];
  unsigned short* As = (unsigned short*)smemf;
  unsigned short* Bs = As + 4096;
  float (*Sc)[132] = (float(*)[132])smemf;
  const int tid = threadIdx.x;
  const int bh = blockIdx.z, h = bh & 3;
  const int m0 = blockIdx.y * 128, n0 = blockIdx.x * 128;
  f32x4 acc[4][4] = {};
  mfma_tile128_glds(ykvbf + (size_t)bh * TT * DD + (size_t)m0 * DD, DD,
                    encvT + (size_t)h * NN * DD + (size_t)n0 * DD, DD, DD, acc, As, Bs);
  const int lane = tid & 63, wave = tid >> 6;
  const int fm = lane & 15, fq = lane >> 4;
  const int cw = (wave & 1) << 6;
  const int rbase = ((wave >> 1) << 4) + (fq << 2);
  const size_t base = (size_t)bh * TT * NN;
  const int rr = tid >> 3, cc = (tid & 7) << 4;
  #pragma unroll
  for (int mi = 0; mi < 4; ++mi) {
    __syncthreads();
    #pragma unroll
    for (int ni = 0; ni < 4; ++ni)
      #pragma unroll
      for (int r = 0; r < 4; ++r)
        Sc[rbase + r][cw + ni * 16 + fm] = acc[mi][ni][r];
    __syncthreads();
    float v[16];
    *(float4*)&v[0]  = *(const float4*)&Sc[rr][cc];
    *(float4*)&v[4]  = *(const float4*)&Sc[rr][cc + 4];
    *(float4*)&v[8]  = *(const float4*)&Sc[rr][cc + 8];
    *(float4*)&v[12] = *(const float4*)&Sc[rr][cc + 12];
    const int t = m0 + ((rr >> 4) << 6) + mi * 16 + (rr & 15);
    const int n = n0 + cc;
    size_t off = base + (size_t)t * NN + n;
    us8 x0 = *(const us8*)(xsp + off);
    us8 x1 = *(const us8*)(xsp + off + 8);
    us8 o0, o1;
    #pragma unroll
    for (int j = 0; j < 8; ++j) {
      o0[j] = f2bf(bf2f(x0[j]) * fmaxf(v[j], 0.0f));
      o1[j] = f2bf(bf2f(x1[j]) * fmaxf(v[8 + j], 0.0f));
    }
    *(us8*)(xy + off) = o0;
    *(us8*)(xy + off + 8) = o1;
  }
}

// ym32[bh*8+ks] = xy_bf chunk @ dec[h] chunk  (K-split 8)
__global__ __launch_bounds__(256) void k_ymlp(const unsigned short* __restrict__ xy,
                                              const unsigned short* __restrict__ decT,
                                              float* __restrict__ ym32) {
  __shared__ float smemf[4096];
  unsigned short* As = (unsigned short*)smemf;
  unsigned short* Bs = As + 4096;
  const int z = blockIdx.z, bh = z >> 3, ks = z & 7, h = bh & 3;
  const int m0 = blockIdx.y * 128, n0 = blockIdx.x * 128;
  f32x4 acc[4][4] = {};
  mfma_tile128_glds(xy + (size_t)bh * TT * NN + (size_t)m0 * NN + ks * 512, NN,
                    decT + (size_t)h * DD * NN + (size_t)n0 * NN + ks * 512, NN,
                    512, acc, As, Bs);
  const int lane = threadIdx.x & 63, wave = threadIdx.x >> 6;
  const int fm = lane & 15, fq = lane >> 4;
  const int rw = (wave >> 1) << 6, cw = (wave & 1) << 6;
  float* C = ym32 + (size_t)z * TT * DD;
  #pragma unroll
  for (int ni = 0; ni < 4; ++ni) {
    int d = n0 + cw + ni * 16 + fm;
    #pragma unroll
    for (int mi = 0; mi < 4; ++mi) {
      int trow = m0 + rw + mi * 16 + (fq << 2);
      #pragma unroll
      for (int r = 0; r < 4; ++r)
        C[(size_t)(trow + r) * DD + d] = acc[mi][ni][r];
    }
  }
}

// x = LN(x + LN(sum of 32 partials)); emits f32 x, bf16 xbf, bf16 xT
__global__ __launch_bounds__(256) void k_ln2(float* __restrict__ x,
                                             const float* __restrict__ ym32,
                                             unsigned short* __restrict__ xbf,
                                             unsigned short* __restrict__ xTbf) {
  int row = blockIdx.x, tid = threadIdx.x;
  int b = row >> 9, t = row & 511;
  float y = 0.0f;
  for (int p = 0; p < 32; ++p)
    y += ym32[(size_t)(b * 32 + p) * TT * DD + (size_t)t * DD + tid];
  float mu = block_sum_256(y) * (1.0f / DD);
  float d = y - mu;
  float var = block_sum_256(d * d) * (1.0f / DD);
  float ly = d * rsqrtf(var + 1e-5f);
  float xv = x[(size_t)row * DD + tid] + ly;
  float mu2 = block_sum_256(xv) * (1.0f / DD);
  float d2 = xv - mu2;
  float var2 = block_sum_256(d2 * d2) * (1.0f / DD);
  float r = d2 * rsqrtf(var2 + 1e-5f);
  x[(size_t)row * DD + tid] = r;
  unsigned short rb = f2bf(r);
  xbf[(size_t)row * DD + tid] = rb;
  xTbf[((size_t)b * DD + tid) * TT + t] = rb;
}

__global__ __launch_bounds__(256) void k_trace(const unsigned short* __restrict__ xy,
                                               float* __restrict__ out) {
  int idx = blockIdx.x * 256 + threadIdx.x;
  int b = idx >> 14, c = idx & 16383;
  int h = c >> 12, n = c & 4095;
  size_t base = (size_t)(b * 4 + h) * TT * NN + n;
  float s = 0.0f;
  for (int t = 0; t < TT; ++t) s += bf2f(xy[base + (size_t)t * NN]);
  out[idx] = s * (1.0f / TT);
}

__global__ __launch_bounds__(256) void k_logits(const float* __restrict__ x,
                                                const float* __restrict__ W,
                                                float* __restrict__ out) {
  __shared__ float xs[DD];
  int row = blockIdx.x, tid = threadIdx.x;
  xs[tid] = x[(size_t)row * DD + tid];
  __syncthreads();
  float s = 0.0f;
  #pragma unroll 8
  for (int d = 0; d < DD; ++d) s = fmaf(xs[d], W[(size_t)d * VV + tid], s);
  out[(size_t)row * VV + tid] = s;
}

__global__ __launch_bounds__(256) void k_embedding(const float* __restrict__ x,
                                                   float* __restrict__ out) {
  int idx = blockIdx.x * 256 + threadIdx.x;
  int b = idx >> 8, d = idx & 255;
  float s = 0.0f;
  for (int t = 0; t < TT; ++t) s += x[(size_t)(b * TT + t) * DD + d];
  out[idx] = s * (1.0f / TT);
}

extern "C" void kernel_launch(void* const* d_in, const int* in_sizes, int n_in,
                              void* d_out, int out_size, void* d_ws, size_t ws_size,
                              hipStream_t stream) {
  const int*   ids  = (const int*)d_in[0];
  const float* tbl  = (const float*)d_in[1];
  const float* enc  = (const float*)d_in[2];
  const float* encv = (const float*)d_in[3];
  const float* dec  = (const float*)d_in[4];
  const float* lmh  = (const float*)d_in[5];

  // workspace layout (float units), ~180 MiB total (195 MiB proven usable in R3)
  float* ws   = (float*)d_ws;
  float* x    = ws;                                              //   262,144 f
  unsigned short* ykvbf = (unsigned short*)(x + 262144);         // 1,048,576 us
  float* ym32 = (float*)(ykvbf + 1048576);                       // 8,388,608 f
  unsigned short* xbf   = (unsigned short*)(ym32 + 8388608);     //   262,144 us
  unsigned short* xTbf  = xbf + 262144;                          //   262,144 us
  unsigned short* encT  = xTbf + 262144;                         // 4,194,304 us
  unsigned short* encvT = encT + 4194304;                        // 4,194,304 us
  unsigned short* decT  = encvT + 4194304;                       // 4,194,304 us
  unsigned short* xspbf = decT + 4194304;                        // 16,777,216 us
  unsigned short* qxybf = xspbf + 16777216;                      // 16,777,216 us
  float2* cs  = (float2*)(qxybf + 16777216);                     // 1,048,576 float2
  float* scp  = (float*)(cs + 1048576);                          // 8,388,608 f (32 MiB)
  float* ykvp = scp + 8388608;                                   // 4,194,304 f (16 MiB)

  float* out_logits = (float*)d_out;
  float* out_embed  = out_logits + (size_t)BB * TT * VV;
  float* out_trace  = out_embed + (size_t)BB * DD;

  k_csinit<<<(TT * NPAIR) / 256, 256, 0, stream>>>(cs);
  k_tcast<<<dim3(NN / 64, DD / 64, NH), 256, 0, stream>>>(enc,  encT,  DD, NN);
  k_tcast<<<dim3(NN / 64, DD / 64, NH), 256, 0, stream>>>(encv, encvT, DD, NN);
  k_tcast<<<dim3(DD / 64, NN / 64, NH), 256, 0, stream>>>(dec,  decT,  NN, DD);

  k_embed_ln<<<BB * TT, 256, 0, stream>>>(ids, tbl, x, xbf, xTbf);
  for (int l = 0; l < NLAYER; ++l) {
    k_enc        <<<dim3(NN / 128, TT / 128, BH), 256, 0, stream>>>(xbf, encT, cs, xspbf, qxybf);
    k_scores_part<<<dim3(TT / 128, TT / 128, BH * 4), 256, 0, stream>>>(qxybf, scp);
    k_ykv_part   <<<dim3(TT / 64, BH, 4), 256, 0, stream>>>(scp, xTbf, ykvp);
    k_ykv_red    <<<BH * TT, 256, 0, stream>>>(ykvp, ykvbf);
    k_ysp_xy     <<<dim3(NN / 128, TT / 128, BH), 256, 0, stream>>>(ykvbf, encvT, xspbf, qxybf);
    k_ymlp       <<<dim3(DD / 128, TT / 128, BH * 8), 256, 0, stream>>>(qxybf, decT, ym32);
    k_ln2        <<<BB * TT, 256, 0, stream>>>(x, ym32, xbf, xTbf);
  }
  k_trace    <<<(BB * NH * NN) / 256, 256, 0, stream>>>(qxybf, out_trace);
  k_logits   <<<BB * TT, 256, 0, stream>>>(x, lmh, out_logits);
  k_embedding<<<(BB * DD) / 256, 256, 0, stream>>>(x, out_embed);
}